// Round 7
// baseline (382.096 us; speedup 1.0000x reference)
//
#include <hip/hip_runtime.h>
#include <math.h>

#define EPS_BN 1e-5f
#define MAXNB 512  // max coarse buckets (N <= 131072); also assumes N < 2^24

typedef __attribute__((ext_vector_type(8))) short bf16x8;
typedef __attribute__((ext_vector_type(4))) float f32x4;
typedef __attribute__((ext_vector_type(2))) float f32x2;

__device__ __forceinline__ ushort f2bf(float f) {
    uint u = __float_as_uint(f);
    u += 0x7FFF + ((u >> 16) & 1);  // RTN-even
    return (ushort)(u >> 16);
}

// ===== prep: 4 weight transposes (f32->bf16^T, CHANNEL-PERMUTED) + bcur + BN tables =====
// Channel permutation: within each 64-col half, Wt row (tc*16+lm) holds actual channel
// (4*lm+tc) -> GEMM thread lm owns 4 CONSECUTIVE output channels (packed stores).
// bnc layout: [sc1(128)|sh1(128)|sc2(128)|sh2(128)|sc3(128)|sh3(128)]
//   sc = g * rsqrt(var+eps); sh = be + (bias - mean) * sc
__global__ __launch_bounds__(256) void prep_k(const float* __restrict__ W1,
                                              const float* __restrict__ W2,
                                              const float* __restrict__ W3,
                                              const float* __restrict__ W4,
                                              ushort* __restrict__ T1,
                                              ushort* __restrict__ T2,
                                              ushort* __restrict__ T3,
                                              ushort* __restrict__ T4,
                                              int* __restrict__ bcur, int NB, int stride,
                                              const float* __restrict__ b1,
                                              const float* __restrict__ g1,
                                              const float* __restrict__ be1,
                                              const float* __restrict__ m1,
                                              const float* __restrict__ v1,
                                              const float* __restrict__ b2,
                                              const float* __restrict__ g2,
                                              const float* __restrict__ be2,
                                              const float* __restrict__ m2,
                                              const float* __restrict__ v2,
                                              const float* __restrict__ b3,
                                              const float* __restrict__ g3,
                                              const float* __restrict__ be3,
                                              const float* __restrict__ m3,
                                              const float* __restrict__ v3,
                                              float* __restrict__ bnc) {
    if (blockIdx.x == 256) {
        for (int i = threadIdx.x; i < NB; i += 256) bcur[i] = i * stride;
        int cc = threadIdx.x & 127;
        int l2 = threadIdx.x >> 7;  // 0: layer1 consts, 1: layer2 consts
        {
            const float* gg = l2 ? g2 : g1;
            const float* bb = l2 ? be2 : be1;
            const float* mm = l2 ? m2 : m1;
            const float* vv = l2 ? v2 : v1;
            const float* bi = l2 ? b2 : b1;
            float s = gg[cc] * rsqrtf(vv[cc] + EPS_BN);
            float* o = bnc + l2 * 256;
            o[cc] = s;
            o[128 + cc] = bb[cc] + (bi[cc] - mm[cc]) * s;
        }
        if (threadIdx.x < 128) {  // layer3 consts
            float s = g3[cc] * rsqrtf(v3[cc] + EPS_BN);
            bnc[512 + cc] = s;
            bnc[640 + cc] = be3[cc] + (b3[cc] - m3[cc]) * s;
        }
        return;
    }
    int which = blockIdx.x >> 6;
    const float* W = (which == 0) ? W1 : (which == 1) ? W2 : (which == 2) ? W3 : W4;
    ushort* T = (which == 0) ? T1 : (which == 1) ? T2 : (which == 2) ? T3 : T4;
    int i = (blockIdx.x & 63) * 256 + threadIdx.x;  // < 16384
    int n = i >> 7, k = i & 127;  // n = actual output channel
    int idx = n & 63;
    int nperm = (n & 64) | ((idx & 3) << 4) | (idx >> 2);  // tc*16 + lm
    T[nperm * 128 + k] = f2bf(W[k * 128 + n]);
}

// ================= bucketed CSR build (fixed-stride buckets) =================
// tile-ranked scatter; coarse entry packed: src | (dst&255)<<24
__global__ __launch_bounds__(256) void bucketA_k(const int* __restrict__ src,
                                                 const int* __restrict__ dst,
                                                 int* __restrict__ bcur,
                                                 int* __restrict__ coarse, int nE, int NB) {
    __shared__ int cnt[MAXNB];
    __shared__ int basix[MAXNB];
    const int tid = threadIdx.x;
    for (int i = tid; i < NB; i += 256) cnt[i] = 0;
    __syncthreads();
    int base = blockIdx.x * 4096;
    int es[16], ed[16], rk[16];
#pragma unroll
    for (int i = 0; i < 16; i++) {
        int e = base + i * 256 + tid;
        if (e < nE) {
            es[i] = src[e];
            ed[i] = dst[e];
            rk[i] = atomicAdd(&cnt[ed[i] >> 8], 1);
        } else {
            ed[i] = -1;
        }
    }
    __syncthreads();
    for (int i = tid; i < NB; i += 256)
        if (cnt[i]) basix[i] = atomicAdd(&bcur[i], cnt[i]);
    __syncthreads();
#pragma unroll
    for (int i = 0; i < 16; i++) {
        if (ed[i] >= 0)
            coarse[basix[ed[i] >> 8] + rk[i]] = es[i] | ((ed[i] & 255) << 24);
    }
}

// per-bucket exact CSR: rowptr(int2)/col/dinv; bucket b owns [b*stride, bcur[b])
__global__ __launch_bounds__(256) void bucketB_k(const int* __restrict__ coarse,
                                                 const int* __restrict__ bcur,
                                                 int2* __restrict__ rowptr,
                                                 int* __restrict__ col,
                                                 float* __restrict__ dinv, int N,
                                                 int stride) {
    __shared__ int cnt[256];
    __shared__ int s[256];
    __shared__ int cur[256];
    const int tid = threadIdx.x;
    const int b = blockIdx.x;
    const int beg = b * stride, end = bcur[b];
    cnt[tid] = 0;
    __syncthreads();
    for (int p = beg + tid; p < end; p += 256)
        atomicAdd(&cnt[((uint)coarse[p]) >> 24], 1);
    __syncthreads();
    int c = cnt[tid];
    s[tid] = c;
    __syncthreads();
    for (int off = 1; off < 256; off <<= 1) {
        int v = (tid >= off) ? s[tid - off] : 0;
        __syncthreads();
        s[tid] += v;
        __syncthreads();
    }
    int ex = s[tid] - c;
    int node = b * 256 + tid;
    if (node < N) {
        rowptr[node] = make_int2(beg + ex, beg + ex + c);
        dinv[node] = rsqrtf((float)c + 1.0f);  // +1 = self loop
    }
    cur[tid] = ex;
    __syncthreads();
    for (int p = beg + tid; p < end; p += 256) {
        int v = coarse[p];
        int r = atomicAdd(&cur[((uint)v) >> 24], 1);
        col[beg + r] = v & 0xFFFFFF;
    }
}

// ============ gather conv over pre-scaled fp8 rows hs = dinv[s]*(XW)[s] ============
__device__ __forceinline__ void add8p(f32x2* acc, uint2 a) {
    acc[0] += __builtin_amdgcn_cvt_pk_f32_fp8(a.x, false);
    acc[1] += __builtin_amdgcn_cvt_pk_f32_fp8(a.x, true);
    acc[2] += __builtin_amdgcn_cvt_pk_f32_fp8(a.y, false);
    acc[3] += __builtin_amdgcn_cvt_pk_f32_fp8(a.y, true);
}

__global__ __launch_bounds__(256) void gather_k(const unsigned char* __restrict__ h8,
                                                const int2* __restrict__ rowptr,
                                                const int* __restrict__ col,
                                                const float* __restrict__ dinv,
                                                const float* __restrict__ sc,
                                                const float* __restrict__ sh,
                                                ushort* __restrict__ out, int n) {
    int node = blockIdx.x * 4 + (threadIdx.x >> 6);
    if (node >= n) return;
    int lane = threadIdx.x & 63;
    int grp = lane >> 4;   // 0..3: edge slot
    int li = lane & 15;    // channel group: 8 ch
    const uint c = (uint)(li * 8);
    const uint c2 = c + (uint)(grp * 2);  // epilogue channel pair for this lane

    // early independent loads (overlap with rowptr->col->row chain)
    int2 rp = rowptr[node];
    float dd = dinv[node];
    f32x2 s2 = *(const f32x2*)(sc + c2);
    f32x2 h2 = *(const f32x2*)(sh + c2);

    int beg = rp.x, end = rp.y;
    int deg = end - beg;
    int nfull = deg >> 4;

    f32x2 acc[4];
#pragma unroll
    for (int j = 0; j < 4; j++) acc[j] = (f32x2){0.f, 0.f};

    if (grp == 0) {  // self loop: hs[d]
        uint2 rv = *(const uint2*)(h8 + (((uint)node << 7) | c));
        add8p(acc, rv);
    }

    // tail col loads: independent of the main loop -> issue now
    int pt = beg + grp + (nfull << 4);
    bool v0 = pt < end, v1 = pt + 4 < end, v2 = pt + 8 < end, v3 = pt + 12 < end;
    int t0 = v0 ? __builtin_nontemporal_load(col + pt) : node;
    int t1 = v1 ? __builtin_nontemporal_load(col + pt + 4) : node;
    int t2 = v2 ? __builtin_nontemporal_load(col + pt + 8) : node;
    int t3 = v3 ? __builtin_nontemporal_load(col + pt + 12) : node;

    int p = beg + grp;
    for (int it = 0; it < nfull; ++it, p += 16) {  // uniform trip count
        int s0 = __builtin_nontemporal_load(col + p);
        int s1 = __builtin_nontemporal_load(col + p + 4);
        int s2i = __builtin_nontemporal_load(col + p + 8);
        int s3 = __builtin_nontemporal_load(col + p + 12);
        uint2 a0 = *(const uint2*)(h8 + (((uint)s0 << 7) | c));
        uint2 a1 = *(const uint2*)(h8 + (((uint)s1 << 7) | c));
        uint2 a2 = *(const uint2*)(h8 + (((uint)s2i << 7) | c));
        uint2 a3 = *(const uint2*)(h8 + (((uint)s3 << 7) | c));
        add8p(acc, a0);
        add8p(acc, a1);
        add8p(acc, a2);
        add8p(acc, a3);
    }
    // unconditional predicated tail (invalid slots read the cache-hot self row,
    // then get zeroed; fp8 0x00 == 0.0f)
    {
        uint2 a0 = *(const uint2*)(h8 + (((uint)t0 << 7) | c));
        uint2 a1 = *(const uint2*)(h8 + (((uint)t1 << 7) | c));
        uint2 a2 = *(const uint2*)(h8 + (((uint)t2 << 7) | c));
        uint2 a3 = *(const uint2*)(h8 + (((uint)t3 << 7) | c));
        if (!v0) { a0.x = 0u; a0.y = 0u; }
        if (!v1) { a1.x = 0u; a1.y = 0u; }
        if (!v2) { a2.x = 0u; a2.y = 0u; }
        if (!v3) { a3.x = 0u; a3.y = 0u; }
        add8p(acc, a0);
        add8p(acc, a1);
        add8p(acc, a2);
        add8p(acc, a3);
    }
    // butterfly reduce: all lanes end with full sums for their 8 channels
#pragma unroll
    for (int j = 0; j < 4; j++) {
        f32x2 t;
        t.x = __shfl_xor(acc[j].x, 16, 64);
        t.y = __shfl_xor(acc[j].y, 16, 64);
        acc[j] += t;
        t.x = __shfl_xor(acc[j].x, 32, 64);
        t.y = __shfl_xor(acc[j].y, 32, 64);
        acc[j] += t;
    }
    // distributed epilogue: lane (grp,li) handles channels c2, c2+1.
    f32x2 pr = (grp == 0) ? acc[0] : (grp == 1) ? acc[1] : (grp == 2) ? acc[2] : acc[3];
    float o0 = fmaxf(fmaf(pr.x * dd, s2.x, h2.x), 0.0f);
    float o1 = fmaxf(fmaf(pr.y * dd, s2.y, h2.y), 0.0f);
    uint r = (uint)f2bf(o0) | ((uint)f2bf(o1) << 16);
    *(uint*)&out[(size_t)node * 128 + c2] = r;
}

// ============ MFMA GEMM: Y = X(n,128) @ W(128,128), fused epilogues ============
// ALL-REGISTER version (no LDS): a wave's entire B-operand (its 64-col half of W,
// all K) is only 64 VGPR -> load it + all A-fragments into registers in a SINGLE
// load phase (24 independent 16B loads in flight), THEN run all 32 MFMAs. No
// barriers (except MODE 2 head), no ds ops. launch_bounds(256,3) keeps VGPR <= ~170
// so the compiler can hold all loads in flight (R4 failed at VGPR=48: serialized).
// W is channel-permuted (see prep_k): thread lm owns output channels cw+4*lm .. +3.
// MODE 0: hs = dinv[row]*v -> fp8 e4m3 (packed dword stores)
// MODE 1: relu(v*sc + sh) -> bf16 (packed uint2 stores); sc/sh precomputed (bnc)
// MODE 2: relu(v+bias) -> f32 nontemporal stores + fused softplus head
// F32IN: input X is f32 (register-staged, converted to bf16, per-tr to limit VGPR)
template <int MODE, int F32IN>
__global__ __launch_bounds__(256, 3) void mfma_gemm_k(const void* __restrict__ Xin,
                                                      const ushort* __restrict__ Wt,
                                                      const float* __restrict__ dinvp,
                                                      const float* __restrict__ bias,
                                                      const float* __restrict__ scp,
                                                      const float* __restrict__ shp,
                                                      const float* __restrict__ Wo,
                                                      const float* __restrict__ bo,
                                                      float* __restrict__ pred,
                                                      void* __restrict__ Y, int nrows) {
    __shared__ float red[64];
    const int tid = threadIdx.x;
    const int row0 = blockIdx.x * 64;
    const int wave = tid >> 6, lane = tid & 63;
    const int rw = (wave >> 1) * 32;
    const int cw = (wave & 1) * 64;
    const int lm = lane & 15, lq = lane >> 4;

    if (MODE == 2) {
        if (tid < 64) red[tid] = 0.0f;
        __syncthreads();
    }

    // ---- phase 1: issue ALL loads ----
    // B fragments: this wave's 64-col half of W, entire K (16 x 16B)
    bf16x8 b[4][4];
    const char* Wb = (const char*)Wt;
#pragma unroll
    for (int tc = 0; tc < 4; tc++) {
        const char* rp = Wb + (cw + tc * 16 + lm) * 256;
#pragma unroll
        for (int ks = 0; ks < 4; ks++)
            b[tc][ks] = *(const bf16x8*)(rp + ks * 64 + lq * 16);
    }
    // A fragments: 2 rows per lane, entire K (8 x 16B)
    int rb = row0 + rw + lm;
    int ra0 = (rb < nrows) ? rb : (nrows - 1);
    int ra1 = (rb + 16 < nrows) ? (rb + 16) : (nrows - 1);
    bf16x8 a[2][4];
    if (F32IN) {
        const float* Xf = (const float*)Xin;
#pragma unroll
        for (int tr = 0; tr < 2; tr++) {
            const float* rp = Xf + (size_t)(tr ? ra1 : ra0) * 128;
#pragma unroll
            for (int ks = 0; ks < 4; ks++) {
                float4 v0 = *(const float4*)(rp + ks * 32 + lq * 8);
                float4 v1 = *(const float4*)(rp + ks * 32 + lq * 8 + 4);
                union { bf16x8 v; ushort u[8]; } t;
                t.u[0] = f2bf(v0.x); t.u[1] = f2bf(v0.y);
                t.u[2] = f2bf(v0.z); t.u[3] = f2bf(v0.w);
                t.u[4] = f2bf(v1.x); t.u[5] = f2bf(v1.y);
                t.u[6] = f2bf(v1.z); t.u[7] = f2bf(v1.w);
                a[tr][ks] = t.v;
            }
        }
    } else {
        const char* Xb = (const char*)Xin;
        const char* rp0 = Xb + (size_t)ra0 * 256;
        const char* rp1 = Xb + (size_t)ra1 * 256;
#pragma unroll
        for (int ks = 0; ks < 4; ks++) {
            a[0][ks] = *(const bf16x8*)(rp0 + ks * 64 + lq * 16);
            a[1][ks] = *(const bf16x8*)(rp1 + ks * 64 + lq * 16);
        }
    }
    // epilogue constants preloaded (latency hides under MFMA phase)
    const int c0 = cw + (lm << 2);
    float psc[4], psh[4], woc[4], ddv[8];
    if (MODE == 1) {
#pragma unroll
        for (int tc = 0; tc < 4; tc++) {
            psc[tc] = scp[c0 + tc];
            psh[tc] = shp[c0 + tc];
        }
    } else if (MODE == 2) {
#pragma unroll
        for (int tc = 0; tc < 4; tc++) {
            psh[tc] = bias[c0 + tc];
            woc[tc] = Wo[c0 + tc];
        }
    } else {
#pragma unroll
        for (int tr = 0; tr < 2; tr++)
#pragma unroll
            for (int r = 0; r < 4; r++) {
                int row = row0 + rw + tr * 16 + lq * 4 + r;
                ddv[tr * 4 + r] = dinvp[(row < nrows) ? row : (nrows - 1)];
            }
    }

    // ---- phase 2: all 32 MFMAs ----
    f32x4 acc[2][4];
#pragma unroll
    for (int tr = 0; tr < 2; tr++)
#pragma unroll
        for (int tc = 0; tc < 4; tc++) acc[tr][tc] = (f32x4){0.f, 0.f, 0.f, 0.f};
#pragma unroll
    for (int ks = 0; ks < 4; ks++)
#pragma unroll
        for (int tr = 0; tr < 2; tr++)
#pragma unroll
            for (int tc = 0; tc < 4; tc++)
                acc[tr][tc] = __builtin_amdgcn_mfma_f32_16x16x32_bf16(a[tr][ks], b[tc][ks],
                                                                      acc[tr][tc], 0, 0, 0);

    // ---- epilogue ----
    float part[8];
    if (MODE == 2) {
#pragma unroll
        for (int i = 0; i < 8; i++) part[i] = 0.0f;
    }
#pragma unroll
    for (int tr = 0; tr < 2; tr++) {
#pragma unroll
        for (int r = 0; r < 4; r++) {
            int row = row0 + rw + tr * 16 + lq * 4 + r;
            if (row >= nrows) continue;
            if (MODE == 0) {
                float dd = ddv[tr * 4 + r];
                uint q = __builtin_amdgcn_cvt_pk_fp8_f32(acc[tr][0][r] * dd,
                                                         acc[tr][1][r] * dd, 0u, false);
                q = __builtin_amdgcn_cvt_pk_fp8_f32(acc[tr][2][r] * dd,
                                                    acc[tr][3][r] * dd, q, true);
                *(uint*)((unsigned char*)Y + (size_t)row * 128 + c0) = q;
            } else if (MODE == 1) {
                float o0 = fmaxf(fmaf(acc[tr][0][r], psc[0], psh[0]), 0.0f);
                float o1 = fmaxf(fmaf(acc[tr][1][r], psc[1], psh[1]), 0.0f);
                float o2 = fmaxf(fmaf(acc[tr][2][r], psc[2], psh[2]), 0.0f);
                float o3 = fmaxf(fmaf(acc[tr][3][r], psc[3], psh[3]), 0.0f);
                uint2 st;
                st.x = (uint)f2bf(o0) | ((uint)f2bf(o1) << 16);
                st.y = (uint)f2bf(o2) | ((uint)f2bf(o3) << 16);
                *(uint2*)((ushort*)Y + (size_t)row * 128 + c0) = st;
            } else {
                float o0 = fmaxf(acc[tr][0][r] + psh[0], 0.0f);
                float o1 = fmaxf(acc[tr][1][r] + psh[1], 0.0f);
                float o2 = fmaxf(acc[tr][2][r] + psh[2], 0.0f);
                float o3 = fmaxf(acc[tr][3][r] + psh[3], 0.0f);
                f32x4 st = {o0, o1, o2, o3};
                __builtin_nontemporal_store(st, (f32x4*)((float*)Y + (size_t)row * 128 + c0));
                part[tr * 4 + r] = fmaf(o0, woc[0],
                                   fmaf(o1, woc[1],
                                   fmaf(o2, woc[2],
                                   fmaf(o3, woc[3], part[tr * 4 + r]))));
            }
        }
    }
    if (MODE == 2) {
#pragma unroll
        for (int tr = 0; tr < 2; tr++)
#pragma unroll
            for (int r = 0; r < 4; r++) {
                int lrow = rw + tr * 16 + lq * 4 + r;
                atomicAdd(&red[lrow], part[tr * 4 + r]);
            }
        __syncthreads();
        if (tid < 64) {
            int row = row0 + tid;
            if (row < nrows) {
                float xv = red[tid] + bo[0];
                pred[row] = fmaxf(xv, 0.0f) + log1pf(expf(-fabsf(xv)));  // softplus
            }
        }
    }
}

extern "C" void kernel_launch(void* const* d_in, const int* in_sizes, int n_in,
                              void* d_out, int out_size, void* d_ws, size_t ws_size,
                              hipStream_t stream) {
    const float* x = (const float*)d_in[0];
    const int* ei = (const int*)d_in[1];
    const int N = in_sizes[0] / 128;
    const int E = in_sizes[1] / 2;
    const int* srcv = ei;
    const int* dstv = ei + E;
    const float* W1 = (const float*)d_in[2];  const float* b1 = (const float*)d_in[3];
    const float* W2 = (const float*)d_in[4];  const float* b2 = (const float*)d_in[5];
    const float* Wf1 = (const float*)d_in[6]; const float* bf1 = (const float*)d_in[7];
    const float* Wf2 = (const float*)d_in[8]; const float* bf2 = (const float*)d_in[9];
    const float* Wo = (const float*)d_in[10]; const float* bo = (const float*)d_in[11];
    const float* g1 = (const float*)d_in[12], *be1 = (const float*)d_in[13],
               *m1 = (const float*)d_in[14], *v1 = (const float*)d_in[15];
    const float* g2 = (const float*)d_in[16], *be2 = (const float*)d_in[17],
               *m2 = (const float*)d_in[18], *v2 = (const float*)d_in[19];
    const float* g3 = (const float*)d_in[20], *be3 = (const float*)d_in[21],
               *m3 = (const float*)d_in[22], *v3 = (const float*)d_in[23];

    // ---- workspace carve-up ----
    char* ws = (char*)d_ws;
    size_t off = 0;
    auto carve = [&](size_t bytes) {
        char* p = ws + off;
        off = (off + bytes + 255) & ~(size_t)255;
        return p;
    };
    const int NB = (N + 255) >> 8;
    const int STRIDE = ((E / NB + 511) + 255) & ~255;  // mean + ~8 sigma slack
    int* bcur = (int*)carve((size_t)MAXNB * 4);
    int2* rowptr = (int2*)carve((size_t)N * 8);
    int* col = (int*)carve((size_t)NB * STRIDE * 4);
    int* coarse = (int*)carve((size_t)NB * STRIDE * 4);
    float* dinv = (float*)carve((size_t)N * 4);
    unsigned char* bufA8 = (unsigned char*)carve((size_t)N * 128 + 16384);  // fp8 hs
    ushort* bufB = (ushort*)carve((size_t)N * 128 * 2 + 16384);             // bf16
    ushort* bufC = (ushort*)carve((size_t)N * 128 * 2 + 16384);             // bf16
    ushort* Wt1 = (ushort*)carve(128 * 128 * 2);
    ushort* Wt2 = (ushort*)carve(128 * 128 * 2);
    ushort* Wtf1 = (ushort*)carve(128 * 128 * 2);
    ushort* Wtf2 = (ushort*)carve(128 * 128 * 2);
    float* bnc = (float*)carve(768 * 4);  // sc1|sh1|sc2|sh2|sc3|sh3

    float* out_pred = (float*)d_out;
    float* out_h1 = out_pred + N;

    const int gblocks = (N + 63) / 64;
    const int tblocks = (E + 4095) / 4096;
    const int wblocks = (N + 3) / 4;

    // ---- prep (weights + bcur + BN consts) ----
    prep_k<<<257, 256, 0, stream>>>(W1, W2, Wf1, Wf2, Wt1, Wt2, Wtf1, Wtf2, bcur, NB,
                                    STRIDE, b1, g1, be1, m1, v1, b2, g2, be2, m2, v2,
                                    bf1, g3, be3, m3, v3, bnc);
    // ---- CSR build ----
    bucketA_k<<<tblocks, 256, 0, stream>>>(srcv, dstv, bcur, coarse, E, NB);
    bucketB_k<<<NB, 256, 0, stream>>>(coarse, bcur, rowptr, col, dinv, N, STRIDE);

    // layer 1: hs1 = dinv*(x@W1) (fp8)
    mfma_gemm_k<0, 1><<<gblocks, 256, 0, stream>>>(x, Wt1, dinv, nullptr, nullptr,
                                                   nullptr, nullptr, nullptr, nullptr,
                                                   bufA8, N);
    // conv1 + bn1 + relu -> bf16
    gather_k<<<wblocks, 256, 0, stream>>>(bufA8, rowptr, col, dinv,
                                          bnc, bnc + 128, bufB, N);
    // layer 2 GEMM: hs2 = dinv*(h@W2) (fp8)
    mfma_gemm_k<0, 0><<<gblocks, 256, 0, stream>>>(bufB, Wt2, dinv, nullptr, nullptr,
                                                   nullptr, nullptr, nullptr, nullptr,
                                                   bufA8, N);
    // conv2 + bn2 + relu -> bf16
    gather_k<<<wblocks, 256, 0, stream>>>(bufA8, rowptr, col, dinv,
                                          bnc + 256, bnc + 384, bufB, N);
    // layer 3: h = relu(bn3(h@Wf1 + bf1)) -> bf16 (sc3/sh3 precomputed)
    mfma_gemm_k<1, 0><<<gblocks, 256, 0, stream>>>(bufB, Wtf1, nullptr, nullptr,
                                                   bnc + 512, bnc + 640, nullptr,
                                                   nullptr, nullptr, bufC, N);
    // layer 4 + head: h1 = relu(h@Wf2 + bf2) -> f32 d_out; pred = softplus(h1@Wo+bo)
    mfma_gemm_k<2, 0><<<gblocks, 256, 0, stream>>>(bufC, Wtf2, nullptr, bf2, nullptr,
                                                   nullptr, Wo, bo,
                                                   out_pred, out_h1, N);
}

// Round 8
// 362.189 us; speedup vs baseline: 1.0550x; 1.0550x over previous
//
#include <hip/hip_runtime.h>
#include <math.h>

#define EPS_BN 1e-5f
#define MAXNB 512  // max coarse buckets (N <= 131072); also assumes N < 2^24

typedef __attribute__((ext_vector_type(8))) short bf16x8;
typedef __attribute__((ext_vector_type(4))) float f32x4;
typedef __attribute__((ext_vector_type(2))) float f32x2;

__device__ __forceinline__ ushort f2bf(float f) {
    uint u = __float_as_uint(f);
    u += 0x7FFF + ((u >> 16) & 1);  // RTN-even
    return (ushort)(u >> 16);
}

// async global->LDS, 16B per lane. LDS dest = wave-uniform base + lane*16 (linear).
__device__ __forceinline__ void gload_lds16(const void* g, void* l) {
    __builtin_amdgcn_global_load_lds((const unsigned int*)g, (unsigned int*)l, 16, 0, 0);
}

// XOR swizzle for bf16 tile rows (256B/row). Applied at produce (global layout,
// pre-swizzled by gather/MODE1 stores) and at the LDS fragment read.
#define SWZ(row, byte_in_row) ((byte_in_row) ^ (((row) & 7) << 4))

// ===== prep: 4 weight transposes (f32->bf16^T, CHANNEL-PERMUTED, linear) + BN tables =====
// Channel permutation: within each 64-col half, Wt row (tc*16+lm) holds actual channel
// (4*lm+tc) -> GEMM thread lm owns 4 CONSECUTIVE output channels (packed stores).
// bnc layout: [sc1(128)|sh1(128)|sc2(128)|sh2(128)|sc3(128)|sh3(128)]
__global__ __launch_bounds__(256) void prep_k(const float* __restrict__ W1,
                                              const float* __restrict__ W2,
                                              const float* __restrict__ W3,
                                              const float* __restrict__ W4,
                                              ushort* __restrict__ T1,
                                              ushort* __restrict__ T2,
                                              ushort* __restrict__ T3,
                                              ushort* __restrict__ T4,
                                              int* __restrict__ bcur, int NB, int stride,
                                              const float* __restrict__ b1,
                                              const float* __restrict__ g1,
                                              const float* __restrict__ be1,
                                              const float* __restrict__ m1,
                                              const float* __restrict__ v1,
                                              const float* __restrict__ b2,
                                              const float* __restrict__ g2,
                                              const float* __restrict__ be2,
                                              const float* __restrict__ m2,
                                              const float* __restrict__ v2,
                                              const float* __restrict__ b3,
                                              const float* __restrict__ g3,
                                              const float* __restrict__ be3,
                                              const float* __restrict__ m3,
                                              const float* __restrict__ v3,
                                              float* __restrict__ bnc) {
    if (blockIdx.x == 256) {
        for (int i = threadIdx.x; i < NB; i += 256) bcur[i] = i * stride;
        int cc = threadIdx.x & 127;
        int l2 = threadIdx.x >> 7;  // 0: layer1 consts, 1: layer2 consts
        {
            const float* gg = l2 ? g2 : g1;
            const float* bb = l2 ? be2 : be1;
            const float* mm = l2 ? m2 : m1;
            const float* vv = l2 ? v2 : v1;
            const float* bi = l2 ? b2 : b1;
            float s = gg[cc] * rsqrtf(vv[cc] + EPS_BN);
            float* o = bnc + l2 * 256;
            o[cc] = s;
            o[128 + cc] = bb[cc] + (bi[cc] - mm[cc]) * s;
        }
        if (threadIdx.x < 128) {  // layer3 consts
            float s = g3[cc] * rsqrtf(v3[cc] + EPS_BN);
            bnc[512 + cc] = s;
            bnc[640 + cc] = be3[cc] + (b3[cc] - m3[cc]) * s;
        }
        return;
    }
    int which = blockIdx.x >> 6;
    const float* W = (which == 0) ? W1 : (which == 1) ? W2 : (which == 2) ? W3 : W4;
    ushort* T = (which == 0) ? T1 : (which == 1) ? T2 : (which == 2) ? T3 : T4;
    int i = (blockIdx.x & 63) * 256 + threadIdx.x;  // < 16384
    int n = i >> 7, k = i & 127;  // n = actual output channel
    int idx = n & 63;
    int nperm = (n & 64) | ((idx & 3) << 4) | (idx >> 2);  // tc*16 + lm
    T[nperm * 128 + k] = f2bf(W[k * 128 + n]);
}

// ================= bucketed CSR build (fixed-stride buckets) =================
// tile-ranked scatter; coarse entry packed: src | (dst&255)<<24
__global__ __launch_bounds__(256) void bucketA_k(const int* __restrict__ src,
                                                 const int* __restrict__ dst,
                                                 int* __restrict__ bcur,
                                                 int* __restrict__ coarse, int nE, int NB) {
    __shared__ int cnt[MAXNB];
    __shared__ int basix[MAXNB];
    const int tid = threadIdx.x;
    for (int i = tid; i < NB; i += 256) cnt[i] = 0;
    __syncthreads();
    int base = blockIdx.x * 4096;
    int es[16], ed[16], rk[16];
#pragma unroll
    for (int i = 0; i < 16; i++) {
        int e = base + i * 256 + tid;
        if (e < nE) {
            es[i] = src[e];
            ed[i] = dst[e];
            rk[i] = atomicAdd(&cnt[ed[i] >> 8], 1);
        } else {
            ed[i] = -1;
        }
    }
    __syncthreads();
    for (int i = tid; i < NB; i += 256)
        if (cnt[i]) basix[i] = atomicAdd(&bcur[i], cnt[i]);
    __syncthreads();
#pragma unroll
    for (int i = 0; i < 16; i++) {
        if (ed[i] >= 0)
            coarse[basix[ed[i] >> 8] + rk[i]] = es[i] | ((ed[i] & 255) << 24);
    }
}

// per-bucket exact CSR: rowptr(int2)/col/dinv; bucket b owns [b*stride, bcur[b])
__global__ __launch_bounds__(256) void bucketB_k(const int* __restrict__ coarse,
                                                 const int* __restrict__ bcur,
                                                 int2* __restrict__ rowptr,
                                                 int* __restrict__ col,
                                                 float* __restrict__ dinv, int N,
                                                 int stride) {
    __shared__ int cnt[256];
    __shared__ int s[256];
    __shared__ int cur[256];
    const int tid = threadIdx.x;
    const int b = blockIdx.x;
    const int beg = b * stride, end = bcur[b];
    cnt[tid] = 0;
    __syncthreads();
    for (int p = beg + tid; p < end; p += 256)
        atomicAdd(&cnt[((uint)coarse[p]) >> 24], 1);
    __syncthreads();
    int c = cnt[tid];
    s[tid] = c;
    __syncthreads();
    for (int off = 1; off < 256; off <<= 1) {
        int v = (tid >= off) ? s[tid - off] : 0;
        __syncthreads();
        s[tid] += v;
        __syncthreads();
    }
    int ex = s[tid] - c;
    int node = b * 256 + tid;
    if (node < N) {
        rowptr[node] = make_int2(beg + ex, beg + ex + c);
        dinv[node] = rsqrtf((float)c + 1.0f);  // +1 = self loop
    }
    cur[tid] = ex;
    __syncthreads();
    for (int p = beg + tid; p < end; p += 256) {
        int v = coarse[p];
        int r = atomicAdd(&cur[((uint)v) >> 24], 1);
        col[beg + r] = v & 0xFFFFFF;
    }
}

// ============ gather conv over pre-scaled fp8 rows hs = dinv[s]*(XW)[s] ============
__device__ __forceinline__ void add8p(f32x2* acc, uint2 a) {
    acc[0] += __builtin_amdgcn_cvt_pk_f32_fp8(a.x, false);
    acc[1] += __builtin_amdgcn_cvt_pk_f32_fp8(a.x, true);
    acc[2] += __builtin_amdgcn_cvt_pk_f32_fp8(a.y, false);
    acc[3] += __builtin_amdgcn_cvt_pk_f32_fp8(a.y, true);
}

__global__ __launch_bounds__(256) void gather_k(const unsigned char* __restrict__ h8,
                                                const int2* __restrict__ rowptr,
                                                const int* __restrict__ col,
                                                const float* __restrict__ dinv,
                                                const float* __restrict__ sc,
                                                const float* __restrict__ sh,
                                                ushort* __restrict__ out, int n) {
    int node = blockIdx.x * 4 + (threadIdx.x >> 6);
    if (node >= n) return;
    int lane = threadIdx.x & 63;
    int grp = lane >> 4;   // 0..3: edge slot
    int li = lane & 15;    // channel group: 8 ch
    const uint c = (uint)(li * 8);
    const uint c2 = c + (uint)(grp * 2);  // epilogue channel pair for this lane

    // early independent loads (overlap with rowptr->col->row chain)
    int2 rp = rowptr[node];
    float dd = dinv[node];
    f32x2 s2 = *(const f32x2*)(sc + c2);
    f32x2 h2 = *(const f32x2*)(sh + c2);

    int beg = rp.x, end = rp.y;
    int deg = end - beg;
    int nfull = deg >> 4;

    f32x2 acc[4];
#pragma unroll
    for (int j = 0; j < 4; j++) acc[j] = (f32x2){0.f, 0.f};

    if (grp == 0) {  // self loop: hs[d]
        uint2 rv = *(const uint2*)(h8 + (((uint)node << 7) | c));
        add8p(acc, rv);
    }

    // tail col loads: independent of the main loop -> issue now
    int pt = beg + grp + (nfull << 4);
    bool v0 = pt < end, v1 = pt + 4 < end, v2 = pt + 8 < end, v3 = pt + 12 < end;
    int t0 = v0 ? __builtin_nontemporal_load(col + pt) : node;
    int t1 = v1 ? __builtin_nontemporal_load(col + pt + 4) : node;
    int t2 = v2 ? __builtin_nontemporal_load(col + pt + 8) : node;
    int t3 = v3 ? __builtin_nontemporal_load(col + pt + 12) : node;

    int p = beg + grp;
    for (int it = 0; it < nfull; ++it, p += 16) {  // uniform trip count
        int s0 = __builtin_nontemporal_load(col + p);
        int s1 = __builtin_nontemporal_load(col + p + 4);
        int s2i = __builtin_nontemporal_load(col + p + 8);
        int s3 = __builtin_nontemporal_load(col + p + 12);
        uint2 a0 = *(const uint2*)(h8 + (((uint)s0 << 7) | c));
        uint2 a1 = *(const uint2*)(h8 + (((uint)s1 << 7) | c));
        uint2 a2 = *(const uint2*)(h8 + (((uint)s2i << 7) | c));
        uint2 a3 = *(const uint2*)(h8 + (((uint)s3 << 7) | c));
        add8p(acc, a0);
        add8p(acc, a1);
        add8p(acc, a2);
        add8p(acc, a3);
    }
    // unconditional predicated tail (invalid slots read the cache-hot self row,
    // then get zeroed; fp8 0x00 == 0.0f)
    {
        uint2 a0 = *(const uint2*)(h8 + (((uint)t0 << 7) | c));
        uint2 a1 = *(const uint2*)(h8 + (((uint)t1 << 7) | c));
        uint2 a2 = *(const uint2*)(h8 + (((uint)t2 << 7) | c));
        uint2 a3 = *(const uint2*)(h8 + (((uint)t3 << 7) | c));
        if (!v0) { a0.x = 0u; a0.y = 0u; }
        if (!v1) { a1.x = 0u; a1.y = 0u; }
        if (!v2) { a2.x = 0u; a2.y = 0u; }
        if (!v3) { a3.x = 0u; a3.y = 0u; }
        add8p(acc, a0);
        add8p(acc, a1);
        add8p(acc, a2);
        add8p(acc, a3);
    }
    // butterfly reduce: all lanes end with full sums for their 8 channels
#pragma unroll
    for (int j = 0; j < 4; j++) {
        f32x2 t;
        t.x = __shfl_xor(acc[j].x, 16, 64);
        t.y = __shfl_xor(acc[j].y, 16, 64);
        acc[j] += t;
        t.x = __shfl_xor(acc[j].x, 32, 64);
        t.y = __shfl_xor(acc[j].y, 32, 64);
        acc[j] += t;
    }
    // distributed epilogue: lane (grp,li) handles channels c2, c2+1.
    // Output row stored SWIZZLED (GEMM copies it linearly into LDS).
    f32x2 pr = (grp == 0) ? acc[0] : (grp == 1) ? acc[1] : (grp == 2) ? acc[2] : acc[3];
    float o0 = fmaxf(fmaf(pr.x * dd, s2.x, h2.x), 0.0f);
    float o1 = fmaxf(fmaf(pr.y * dd, s2.y, h2.y), 0.0f);
    uint r = (uint)f2bf(o0) | ((uint)f2bf(o1) << 16);
    uint boff = ((uint)node << 8) + SWZ((uint)node, c2 * 2);
    *(uint*)((char*)out + boff) = r;
}

// ============ MFMA GEMM: Y = X(n,128) @ W(128,128), fused epilogues ============
// 128 rows/block = 2 subtiles of 64. W in REGISTERS (b[4][4], 64 VGPR), loaded once
// from L2 and reused by BOTH subtiles -> loop-carried liveness forces register
// residency (R4/R7 failure was single-use chains). X staged via global_load_lds into
// a 2x16KB double buffer; subtile-1 stage issued before subtile-0 compute so HBM
// latency hides under ds_read+MFMA (T3 minimal 2-phase).
// W is channel-permuted (see prep_k): thread lm owns output channels cw+4*lm .. +3.
// MODE 0: hs = dinv[row]*v -> fp8 e4m3 (packed dword stores, unswizzled)
// MODE 1: relu(v*sc + sh) -> bf16 (packed uint2 stores, SWIZZLED: next GEMM reads)
// MODE 2: relu(v+bias) -> f32 nontemporal stores + fused softplus head
// F32IN: input X is f32 (register-staged both subtiles, converted, swizzled ds_write)
template <int MODE, int F32IN>
__global__ __launch_bounds__(256, 3) void mfma_gemm_k(const void* __restrict__ Xin,
                                                      const ushort* __restrict__ Wt,
                                                      const float* __restrict__ dinvp,
                                                      const float* __restrict__ bias,
                                                      const float* __restrict__ scp,
                                                      const float* __restrict__ shp,
                                                      const float* __restrict__ Wo,
                                                      const float* __restrict__ bo,
                                                      float* __restrict__ pred,
                                                      void* __restrict__ Y, int nrows) {
    __shared__ ushort sX0[64 * 128];  // 16KB, subtile 0 (swizzled rows)
    __shared__ ushort sX1[64 * 128];  // 16KB, subtile 1
    __shared__ float red[128];
    const int tid = threadIdx.x;
    const int row0 = blockIdx.x * 128;
    const int wave = tid >> 6, lane = tid & 63;
    const int rw = (wave >> 1) * 32;
    const int cw = (wave & 1) * 64;
    const int lm = lane & 15, lq = lane >> 4;

    // ---- B-operand: this wave's 64-col half of W, all K, in registers ----
    bf16x8 b[4][4];
    const char* Wb = (const char*)Wt;
#pragma unroll
    for (int tc = 0; tc < 4; tc++) {
        const char* rp = Wb + (cw + tc * 16 + lm) * 256;
#pragma unroll
        for (int ks = 0; ks < 4; ks++)
            b[tc][ks] = *(const bf16x8*)(rp + ks * 64 + lq * 16);
    }

    // ---- stage X subtile 0 (and both, if F32IN) ----
    if (F32IN) {
        const float* Xf = (const float*)Xin;
#pragma unroll
        for (int i = 0; i < 8; i++) {
            int chunk = i * 256 + tid;          // 2048 chunks of 16B over 128 rows
            int r = chunk >> 4;                 // local row 0..127
            int cb = (chunk & 15) * 16;         // byte offset in bf16 row
            int rg = row0 + r;
            if (rg >= nrows) rg = nrows - 1;
            const float* rp = &Xf[(size_t)rg * 128 + cb / 2];
            float4 v0 = *(const float4*)rp;
            float4 v1 = *(const float4*)(rp + 4);
            union { bf16x8 v; ushort u[8]; } t;
            t.u[0] = f2bf(v0.x); t.u[1] = f2bf(v0.y);
            t.u[2] = f2bf(v0.z); t.u[3] = f2bf(v0.w);
            t.u[4] = f2bf(v1.x); t.u[5] = f2bf(v1.y);
            t.u[6] = f2bf(v1.z); t.u[7] = f2bf(v1.w);
            char* base = (r < 64) ? (char*)sX0 : (char*)sX1;
            int rl = r & 63;
            *(bf16x8*)(base + (rl << 8) + SWZ(rl, cb)) = t.v;
        }
    } else {
        const char* gX = (const char*)Xin;  // bf16 rows stored pre-swizzled
#pragma unroll
        for (int i = 0; i < 4; i++) {
            int off = wave * 4096 + i * 1024 + lane * 16;
            int rg = row0 + (off >> 8);
            if (rg >= nrows) rg = nrows - 1;
            gload_lds16(gX + (size_t)rg * 256 + (off & 255), (char*)sX0 + off);
        }
    }
    if (MODE == 2 && tid < 128) red[tid] = 0.0f;
    __syncthreads();  // X0 (and b) ready

    if (!F32IN) {
        // issue subtile-1 stage now; its latency hides under subtile-0 compute
        const char* gX = (const char*)Xin;
#pragma unroll
        for (int i = 0; i < 4; i++) {
            int off = wave * 4096 + i * 1024 + lane * 16;
            int rg = row0 + 64 + (off >> 8);
            if (rg >= nrows) rg = nrows - 1;
            gload_lds16(gX + (size_t)rg * 256 + (off & 255), (char*)sX1 + off);
        }
    }

    // epilogue constants (shared across subtiles)
    const int c0 = cw + (lm << 2);
    float psc[4], psh[4], woc[4];
    if (MODE == 1) {
#pragma unroll
        for (int tc = 0; tc < 4; tc++) { psc[tc] = scp[c0 + tc]; psh[tc] = shp[c0 + tc]; }
    } else if (MODE == 2) {
#pragma unroll
        for (int tc = 0; tc < 4; tc++) { psh[tc] = bias[c0 + tc]; woc[tc] = Wo[c0 + tc]; }
    }

    // ---- per-subtile compute (ds_read fragments, 32 MFMA, fused epilogue) ----
    auto compute = [&](const ushort* sX, int sbase) {
        f32x4 acc[2][4];
#pragma unroll
        for (int tr = 0; tr < 2; tr++)
#pragma unroll
            for (int tc = 0; tc < 4; tc++) acc[tr][tc] = (f32x4){0.f, 0.f, 0.f, 0.f};
#pragma unroll
        for (int ks = 0; ks < 4; ks++) {
            int kbyte = ks * 64 + lq * 16;
            int r0 = rw + lm, r1 = rw + 16 + lm;
            bf16x8 a0 = *(const bf16x8*)((const char*)sX + (r0 << 8) + SWZ(r0, kbyte));
            bf16x8 a1 = *(const bf16x8*)((const char*)sX + (r1 << 8) + SWZ(r1, kbyte));
#pragma unroll
            for (int tc = 0; tc < 4; tc++) {
                acc[0][tc] = __builtin_amdgcn_mfma_f32_16x16x32_bf16(a0, b[tc][ks],
                                                                     acc[0][tc], 0, 0, 0);
                acc[1][tc] = __builtin_amdgcn_mfma_f32_16x16x32_bf16(a1, b[tc][ks],
                                                                     acc[1][tc], 0, 0, 0);
            }
        }
        float part[8];
        if (MODE == 2) {
#pragma unroll
            for (int i = 0; i < 8; i++) part[i] = 0.0f;
        }
#pragma unroll
        for (int tr = 0; tr < 2; tr++) {
#pragma unroll
            for (int r = 0; r < 4; r++) {
                int lrow = sbase + rw + tr * 16 + lq * 4 + r;
                int row = row0 + lrow;
                if (row >= nrows) continue;
                if (MODE == 0) {
                    float dd = dinvp[row];
                    uint q = __builtin_amdgcn_cvt_pk_fp8_f32(acc[tr][0][r] * dd,
                                                             acc[tr][1][r] * dd, 0u, false);
                    q = __builtin_amdgcn_cvt_pk_fp8_f32(acc[tr][2][r] * dd,
                                                        acc[tr][3][r] * dd, q, true);
                    *(uint*)((unsigned char*)Y + (size_t)row * 128 + c0) = q;
                } else if (MODE == 1) {
                    float o0 = fmaxf(fmaf(acc[tr][0][r], psc[0], psh[0]), 0.0f);
                    float o1 = fmaxf(fmaf(acc[tr][1][r], psc[1], psh[1]), 0.0f);
                    float o2 = fmaxf(fmaf(acc[tr][2][r], psc[2], psh[2]), 0.0f);
                    float o3 = fmaxf(fmaf(acc[tr][3][r], psc[3], psh[3]), 0.0f);
                    uint2 st;
                    st.x = (uint)f2bf(o0) | ((uint)f2bf(o1) << 16);
                    st.y = (uint)f2bf(o2) | ((uint)f2bf(o3) << 16);
                    uint boff = ((uint)row << 8) + SWZ((uint)row, (uint)(c0 * 2));
                    *(uint2*)((char*)Y + boff) = st;
                } else {
                    float o0 = fmaxf(acc[tr][0][r] + psh[0], 0.0f);
                    float o1 = fmaxf(acc[tr][1][r] + psh[1], 0.0f);
                    float o2 = fmaxf(acc[tr][2][r] + psh[2], 0.0f);
                    float o3 = fmaxf(acc[tr][3][r] + psh[3], 0.0f);
                    f32x4 st = {o0, o1, o2, o3};
                    __builtin_nontemporal_store(st,
                        (f32x4*)((float*)Y + (size_t)row * 128 + c0));
                    part[tr * 4 + r] = fmaf(o0, woc[0],
                                       fmaf(o1, woc[1],
                                       fmaf(o2, woc[2],
                                       fmaf(o3, woc[3], part[tr * 4 + r]))));
                }
            }
        }
        if (MODE == 2) {
#pragma unroll
            for (int tr = 0; tr < 2; tr++)
#pragma unroll
                for (int r = 0; r < 4; r++)
                    atomicAdd(&red[sbase + rw + tr * 16 + lq * 4 + r], part[tr * 4 + r]);
        }
    };

    compute(sX0, 0);
    __syncthreads();  // X1 ready (issued ~1 compute-phase ago)
    compute(sX1, 64);

    if (MODE == 2) {
        __syncthreads();
        if (tid < 128) {
            int row = row0 + tid;
            if (row < nrows) {
                float xv = red[tid] + bo[0];
                pred[row] = fmaxf(xv, 0.0f) + log1pf(expf(-fabsf(xv)));  // softplus
            }
        }
    }
}

extern "C" void kernel_launch(void* const* d_in, const int* in_sizes, int n_in,
                              void* d_out, int out_size, void* d_ws, size_t ws_size,
                              hipStream_t stream) {
    const float* x = (const float*)d_in[0];
    const int* ei = (const int*)d_in[1];
    const int N = in_sizes[0] / 128;
    const int E = in_sizes[1] / 2;
    const int* srcv = ei;
    const int* dstv = ei + E;
    const float* W1 = (const float*)d_in[2];  const float* b1 = (const float*)d_in[3];
    const float* W2 = (const float*)d_in[4];  const float* b2 = (const float*)d_in[5];
    const float* Wf1 = (const float*)d_in[6]; const float* bf1 = (const float*)d_in[7];
    const float* Wf2 = (const float*)d_in[8]; const float* bf2 = (const float*)d_in[9];
    const float* Wo = (const float*)d_in[10]; const float* bo = (const float*)d_in[11];
    const float* g1 = (const float*)d_in[12], *be1 = (const float*)d_in[13],
               *m1 = (const float*)d_in[14], *v1 = (const float*)d_in[15];
    const float* g2 = (const float*)d_in[16], *be2 = (const float*)d_in[17],
               *m2 = (const float*)d_in[18], *v2 = (const float*)d_in[19];
    const float* g3 = (const float*)d_in[20], *be3 = (const float*)d_in[21],
               *m3 = (const float*)d_in[22], *v3 = (const float*)d_in[23];

    // ---- workspace carve-up ----
    char* ws = (char*)d_ws;
    size_t off = 0;
    auto carve = [&](size_t bytes) {
        char* p = ws + off;
        off = (off + bytes + 255) & ~(size_t)255;
        return p;
    };
    const int NB = (N + 255) >> 8;
    const int STRIDE = ((E / NB + 511) + 255) & ~255;  // mean + ~8 sigma slack
    int* bcur = (int*)carve((size_t)MAXNB * 4);
    int2* rowptr = (int2*)carve((size_t)N * 8);
    int* col = (int*)carve((size_t)NB * STRIDE * 4);
    int* coarse = (int*)carve((size_t)NB * STRIDE * 4);
    float* dinv = (float*)carve((size_t)N * 4);
    unsigned char* bufA8 = (unsigned char*)carve((size_t)N * 128 + 16384);  // fp8 hs
    ushort* bufB = (ushort*)carve((size_t)N * 128 * 2 + 32768);             // bf16 swz
    ushort* bufC = (ushort*)carve((size_t)N * 128 * 2 + 32768);             // bf16 swz
    ushort* Wt1 = (ushort*)carve(128 * 128 * 2);
    ushort* Wt2 = (ushort*)carve(128 * 128 * 2);
    ushort* Wtf1 = (ushort*)carve(128 * 128 * 2);
    ushort* Wtf2 = (ushort*)carve(128 * 128 * 2);
    float* bnc = (float*)carve(768 * 4);  // sc1|sh1|sc2|sh2|sc3|sh3

    float* out_pred = (float*)d_out;
    float* out_h1 = out_pred + N;

    const int gblocks = (N + 127) / 128;
    const int tblocks = (E + 4095) / 4096;
    const int wblocks = (N + 3) / 4;

    // ---- prep (weights + bcur + BN consts) ----
    prep_k<<<257, 256, 0, stream>>>(W1, W2, Wf1, Wf2, Wt1, Wt2, Wtf1, Wtf2, bcur, NB,
                                    STRIDE, b1, g1, be1, m1, v1, b2, g2, be2, m2, v2,
                                    bf1, g3, be3, m3, v3, bnc);
    // ---- CSR build ----
    bucketA_k<<<tblocks, 256, 0, stream>>>(srcv, dstv, bcur, coarse, E, NB);
    bucketB_k<<<NB, 256, 0, stream>>>(coarse, bcur, rowptr, col, dinv, N, STRIDE);

    // layer 1: hs1 = dinv*(x@W1) (fp8)
    mfma_gemm_k<0, 1><<<gblocks, 256, 0, stream>>>(x, Wt1, dinv, nullptr, nullptr,
                                                   nullptr, nullptr, nullptr, nullptr,
                                                   bufA8, N);
    // conv1 + bn1 + relu -> bf16 (swizzled rows)
    gather_k<<<wblocks, 256, 0, stream>>>(bufA8, rowptr, col, dinv,
                                          bnc, bnc + 128, bufB, N);
    // layer 2 GEMM: hs2 = dinv*(h@W2) (fp8)
    mfma_gemm_k<0, 0><<<gblocks, 256, 0, stream>>>(bufB, Wt2, dinv, nullptr, nullptr,
                                                   nullptr, nullptr, nullptr, nullptr,
                                                   bufA8, N);
    // conv2 + bn2 + relu -> bf16 (swizzled rows)
    gather_k<<<wblocks, 256, 0, stream>>>(bufA8, rowptr, col, dinv,
                                          bnc + 256, bnc + 384, bufB, N);
    // layer 3: h = relu(bn3(h@Wf1 + bf1)) -> bf16 swizzled (sc3/sh3 precomputed)
    mfma_gemm_k<1, 0><<<gblocks, 256, 0, stream>>>(bufB, Wtf1, nullptr, nullptr,
                                                   bnc + 512, bnc + 640, nullptr,
                                                   nullptr, nullptr, bufC, N);
    // layer 4 + head: h1 = relu(h@Wf2 + bf2) -> f32 d_out; pred = softplus(h1@Wo+bo)
    mfma_gemm_k<2, 0><<<gblocks, 256, 0, stream>>>(bufC, Wtf2, nullptr, bf2, nullptr,
                                                   nullptr, Wo, bo,
                                                   out_pred, out_h1, N);
}

// Round 9
// 328.102 us; speedup vs baseline: 1.1646x; 1.1039x over previous
//
#include <hip/hip_runtime.h>
#include <math.h>

#define EPS_BN 1e-5f
#define MAXNB 512  // max coarse buckets (N <= 131072); also assumes N < 2^24

typedef __attribute__((ext_vector_type(8))) short bf16x8;
typedef __attribute__((ext_vector_type(4))) float f32x4;
typedef __attribute__((ext_vector_type(2))) float f32x2;

__device__ __forceinline__ ushort f2bf(float f) {
    uint u = __float_as_uint(f);
    u += 0x7FFF + ((u >> 16) & 1);  // RTN-even
    return (ushort)(u >> 16);
}

// async global->LDS, 16B per lane. LDS dest = wave-uniform base + lane*16 (linear).
__device__ __forceinline__ void gload_lds16(const void* g, void* l) {
    __builtin_amdgcn_global_load_lds((const unsigned int*)g, (unsigned int*)l, 16, 0, 0);
}

// XOR swizzle for bf16 tile rows (256B/row): spreads the 16-lane row-column reads
// across 8 bank groups. Applied IDENTICALLY at produce (global layout) and ds_read.
#define SWZ(row, byte_in_row) ((byte_in_row) ^ (((row) & 7) << 4))

// ===== prep: 4 weight transposes (f32->bf16^T, CHANNEL-PERMUTED + SWIZZLED) =====
// Channel permutation: within each 64-col half, Wt row (tc*16+lm) holds actual channel
// (4*lm+tc) -> GEMM thread lm owns 4 CONSECUTIVE output channels (packed stores).
// Swizzle: element (nperm, k) stored at byte nperm*256 + SWZ(nperm, k*2), so a LINEAR
// global_load_lds copy lands it where the swizzled ds_read expects it.
// bnc layout: [sc1(128)|sh1(128)|sc2(128)|sh2(128)|sc3(128)|sh3(128)]
__global__ __launch_bounds__(256) void prep_k(const float* __restrict__ W1,
                                              const float* __restrict__ W2,
                                              const float* __restrict__ W3,
                                              const float* __restrict__ W4,
                                              ushort* __restrict__ T1,
                                              ushort* __restrict__ T2,
                                              ushort* __restrict__ T3,
                                              ushort* __restrict__ T4,
                                              int* __restrict__ bcur, int NB, int stride,
                                              const float* __restrict__ b1,
                                              const float* __restrict__ g1,
                                              const float* __restrict__ be1,
                                              const float* __restrict__ m1,
                                              const float* __restrict__ v1,
                                              const float* __restrict__ b2,
                                              const float* __restrict__ g2,
                                              const float* __restrict__ be2,
                                              const float* __restrict__ m2,
                                              const float* __restrict__ v2,
                                              const float* __restrict__ b3,
                                              const float* __restrict__ g3,
                                              const float* __restrict__ be3,
                                              const float* __restrict__ m3,
                                              const float* __restrict__ v3,
                                              float* __restrict__ bnc) {
    if (blockIdx.x == 256) {
        for (int i = threadIdx.x; i < NB; i += 256) bcur[i] = i * stride;
        int cc = threadIdx.x & 127;
        int l2 = threadIdx.x >> 7;  // 0: layer1 consts, 1: layer2 consts
        {
            const float* gg = l2 ? g2 : g1;
            const float* bb = l2 ? be2 : be1;
            const float* mm = l2 ? m2 : m1;
            const float* vv = l2 ? v2 : v1;
            const float* bi = l2 ? b2 : b1;
            float s = gg[cc] * rsqrtf(vv[cc] + EPS_BN);
            float* o = bnc + l2 * 256;
            o[cc] = s;
            o[128 + cc] = bb[cc] + (bi[cc] - mm[cc]) * s;
        }
        if (threadIdx.x < 128) {  // layer3 consts
            float s = g3[cc] * rsqrtf(v3[cc] + EPS_BN);
            bnc[512 + cc] = s;
            bnc[640 + cc] = be3[cc] + (b3[cc] - m3[cc]) * s;
        }
        return;
    }
    int which = blockIdx.x >> 6;
    const float* W = (which == 0) ? W1 : (which == 1) ? W2 : (which == 2) ? W3 : W4;
    ushort* T = (which == 0) ? T1 : (which == 1) ? T2 : (which == 2) ? T3 : T4;
    int i = (blockIdx.x & 63) * 256 + threadIdx.x;  // < 16384
    int n = i >> 7, k = i & 127;  // n = actual output channel
    int idx = n & 63;
    int nperm = (n & 64) | ((idx & 3) << 4) | (idx >> 2);  // tc*16 + lm
    uint boff = ((uint)nperm << 8) + SWZ(nperm, (uint)k * 2);
    *(ushort*)((char*)T + boff) = f2bf(W[k * 128 + n]);
}

// ================= bucketed CSR build (fixed-stride buckets) =================
// tile-ranked scatter; coarse entry packed: src | (dst&255)<<24
__global__ __launch_bounds__(256) void bucketA_k(const int* __restrict__ src,
                                                 const int* __restrict__ dst,
                                                 int* __restrict__ bcur,
                                                 int* __restrict__ coarse, int nE, int NB) {
    __shared__ int cnt[MAXNB];
    __shared__ int basix[MAXNB];
    const int tid = threadIdx.x;
    for (int i = tid; i < NB; i += 256) cnt[i] = 0;
    __syncthreads();
    int base = blockIdx.x * 4096;
    int es[16], ed[16], rk[16];
#pragma unroll
    for (int i = 0; i < 16; i++) {
        int e = base + i * 256 + tid;
        if (e < nE) {
            es[i] = src[e];
            ed[i] = dst[e];
            rk[i] = atomicAdd(&cnt[ed[i] >> 8], 1);
        } else {
            ed[i] = -1;
        }
    }
    __syncthreads();
    for (int i = tid; i < NB; i += 256)
        if (cnt[i]) basix[i] = atomicAdd(&bcur[i], cnt[i]);
    __syncthreads();
#pragma unroll
    for (int i = 0; i < 16; i++) {
        if (ed[i] >= 0)
            coarse[basix[ed[i] >> 8] + rk[i]] = es[i] | ((ed[i] & 255) << 24);
    }
}

// per-bucket exact CSR: rowptr(int2)/col/dinv; bucket b owns [b*stride, bcur[b])
__global__ __launch_bounds__(256) void bucketB_k(const int* __restrict__ coarse,
                                                 const int* __restrict__ bcur,
                                                 int2* __restrict__ rowptr,
                                                 int* __restrict__ col,
                                                 float* __restrict__ dinv, int N,
                                                 int stride) {
    __shared__ int cnt[256];
    __shared__ int s[256];
    __shared__ int cur[256];
    const int tid = threadIdx.x;
    const int b = blockIdx.x;
    const int beg = b * stride, end = bcur[b];
    cnt[tid] = 0;
    __syncthreads();
    for (int p = beg + tid; p < end; p += 256)
        atomicAdd(&cnt[((uint)coarse[p]) >> 24], 1);
    __syncthreads();
    int c = cnt[tid];
    s[tid] = c;
    __syncthreads();
    for (int off = 1; off < 256; off <<= 1) {
        int v = (tid >= off) ? s[tid - off] : 0;
        __syncthreads();
        s[tid] += v;
        __syncthreads();
    }
    int ex = s[tid] - c;
    int node = b * 256 + tid;
    if (node < N) {
        rowptr[node] = make_int2(beg + ex, beg + ex + c);
        dinv[node] = rsqrtf((float)c + 1.0f);  // +1 = self loop
    }
    cur[tid] = ex;
    __syncthreads();
    for (int p = beg + tid; p < end; p += 256) {
        int v = coarse[p];
        int r = atomicAdd(&cur[((uint)v) >> 24], 1);
        col[beg + r] = v & 0xFFFFFF;
    }
}

// ============ gather conv over pre-scaled fp8 rows hs = dinv[s]*(XW)[s] ============
__device__ __forceinline__ void add8p(f32x2* acc, uint2 a) {
    acc[0] += __builtin_amdgcn_cvt_pk_f32_fp8(a.x, false);
    acc[1] += __builtin_amdgcn_cvt_pk_f32_fp8(a.x, true);
    acc[2] += __builtin_amdgcn_cvt_pk_f32_fp8(a.y, false);
    acc[3] += __builtin_amdgcn_cvt_pk_f32_fp8(a.y, true);
}

__global__ __launch_bounds__(256) void gather_k(const unsigned char* __restrict__ h8,
                                                const int2* __restrict__ rowptr,
                                                const int* __restrict__ col,
                                                const float* __restrict__ dinv,
                                                const float* __restrict__ sc,
                                                const float* __restrict__ sh,
                                                ushort* __restrict__ out, int n) {
    int node = blockIdx.x * 4 + (threadIdx.x >> 6);
    if (node >= n) return;
    int lane = threadIdx.x & 63;
    int grp = lane >> 4;   // 0..3: edge slot
    int li = lane & 15;    // channel group: 8 ch
    const uint c = (uint)(li * 8);
    const uint c2 = c + (uint)(grp * 2);  // epilogue channel pair for this lane

    // early independent loads (overlap with rowptr->col->row chain)
    int2 rp = rowptr[node];
    float dd = dinv[node];
    f32x2 s2 = *(const f32x2*)(sc + c2);
    f32x2 h2 = *(const f32x2*)(sh + c2);

    int beg = rp.x, end = rp.y;
    int deg = end - beg;
    int nfull = deg >> 4;

    f32x2 acc[4];
#pragma unroll
    for (int j = 0; j < 4; j++) acc[j] = (f32x2){0.f, 0.f};

    if (grp == 0) {  // self loop: hs[d]
        uint2 rv = *(const uint2*)(h8 + (((uint)node << 7) | c));
        add8p(acc, rv);
    }

    // tail col loads: independent of the main loop -> issue now
    int pt = beg + grp + (nfull << 4);
    bool v0 = pt < end, v1 = pt + 4 < end, v2 = pt + 8 < end, v3 = pt + 12 < end;
    int t0 = v0 ? __builtin_nontemporal_load(col + pt) : node;
    int t1 = v1 ? __builtin_nontemporal_load(col + pt + 4) : node;
    int t2 = v2 ? __builtin_nontemporal_load(col + pt + 8) : node;
    int t3 = v3 ? __builtin_nontemporal_load(col + pt + 12) : node;

    int p = beg + grp;
    for (int it = 0; it < nfull; ++it, p += 16) {  // uniform trip count
        int s0 = __builtin_nontemporal_load(col + p);
        int s1 = __builtin_nontemporal_load(col + p + 4);
        int s2i = __builtin_nontemporal_load(col + p + 8);
        int s3 = __builtin_nontemporal_load(col + p + 12);
        uint2 a0 = *(const uint2*)(h8 + (((uint)s0 << 7) | c));
        uint2 a1 = *(const uint2*)(h8 + (((uint)s1 << 7) | c));
        uint2 a2 = *(const uint2*)(h8 + (((uint)s2i << 7) | c));
        uint2 a3 = *(const uint2*)(h8 + (((uint)s3 << 7) | c));
        add8p(acc, a0);
        add8p(acc, a1);
        add8p(acc, a2);
        add8p(acc, a3);
    }
    // unconditional predicated tail (invalid slots read the cache-hot self row,
    // then get zeroed; fp8 0x00 == 0.0f)
    {
        uint2 a0 = *(const uint2*)(h8 + (((uint)t0 << 7) | c));
        uint2 a1 = *(const uint2*)(h8 + (((uint)t1 << 7) | c));
        uint2 a2 = *(const uint2*)(h8 + (((uint)t2 << 7) | c));
        uint2 a3 = *(const uint2*)(h8 + (((uint)t3 << 7) | c));
        if (!v0) { a0.x = 0u; a0.y = 0u; }
        if (!v1) { a1.x = 0u; a1.y = 0u; }
        if (!v2) { a2.x = 0u; a2.y = 0u; }
        if (!v3) { a3.x = 0u; a3.y = 0u; }
        add8p(acc, a0);
        add8p(acc, a1);
        add8p(acc, a2);
        add8p(acc, a3);
    }
    // butterfly reduce: all lanes end with full sums for their 8 channels
#pragma unroll
    for (int j = 0; j < 4; j++) {
        f32x2 t;
        t.x = __shfl_xor(acc[j].x, 16, 64);
        t.y = __shfl_xor(acc[j].y, 16, 64);
        acc[j] += t;
        t.x = __shfl_xor(acc[j].x, 32, 64);
        t.y = __shfl_xor(acc[j].y, 32, 64);
        acc[j] += t;
    }
    // distributed epilogue: lane (grp,li) handles channels c2, c2+1.
    // Output row stored SWIZZLED (consumers copy it linearly into LDS).
    f32x2 pr = (grp == 0) ? acc[0] : (grp == 1) ? acc[1] : (grp == 2) ? acc[2] : acc[3];
    float o0 = fmaxf(fmaf(pr.x * dd, s2.x, h2.x), 0.0f);
    float o1 = fmaxf(fmaf(pr.y * dd, s2.y, h2.y), 0.0f);
    uint r = (uint)f2bf(o0) | ((uint)f2bf(o1) << 16);
    uint boff = ((uint)node << 8) + SWZ((uint)node, c2 * 2);
    *(uint*)((char*)out + boff) = r;
}

// ============ MFMA GEMM (R5 structure): Y = X(n,128) @ W(128,128) ============
// LDS staging via global_load_lds width=16 (linear dest); bank conflicts handled by
// the XOR swizzle baked into the GLOBAL layout of Wt/bufB (rule: both-sides).
// W is channel-permuted (see prep_k): thread lm owns output channels cw+4*lm .. +3.
// MODE 0: hs = dinv[row]*v -> fp8 e4m3 (packed dword stores, unswizzled)
// F32IN: input X is f32 (register-staged, converted to bf16, swizzled ds_write)
template <int MODE, int F32IN>
__global__ __launch_bounds__(256) void mfma_gemm_k(const void* __restrict__ Xin,
                                                   const ushort* __restrict__ Wt,
                                                   const float* __restrict__ dinvp,
                                                   void* __restrict__ Y, int nrows) {
    __shared__ ushort sX[64 * 128];   // 16KB, linear+swizzled
    __shared__ ushort sW[128 * 128];  // 32KB, linear+swizzled
    const int tid = threadIdx.x;
    const int row0 = blockIdx.x * 64;
    const int wave = tid >> 6, lane = tid & 63;

    // ---- stage W: straight 32KB linear async copy (pre-swizzled in memory) ----
    {
        const char* gW = (const char*)Wt;
#pragma unroll
        for (int i = 0; i < 8; i++) {
            int base = (wave * 8 + i) * 1024;
            gload_lds16(gW + base + lane * 16, (char*)sW + base);
        }
    }
    // ---- stage X ----
    if (F32IN) {
        const float* Xf = (const float*)Xin;
#pragma unroll
        for (int i = 0; i < 8; i++) {
            int cidx = tid + i * 256;          // 2048 chunks of 8B
            int r = cidx >> 5, o = cidx & 31;  // local row, 8B chunk
            int rg = row0 + r;
            if (rg >= nrows) rg = nrows - 1;
            float4 v = *(const float4*)&((const float*)Xin)[(size_t)rg * 128 + o * 4];
            ushort4 u = {f2bf(v.x), f2bf(v.y), f2bf(v.z), f2bf(v.w)};
            *(ushort4*)((char*)sX + (r << 8) + SWZ(r, o * 8)) = u;
        }
    } else {
        const char* gX = (const char*)Xin;  // bf16 rows stored swizzled
#pragma unroll
        for (int i = 0; i < 4; i++) {
            int base = (wave * 4 + i) * 1024;
            int off = base + lane * 16;
            int rg = row0 + (off >> 8);
            if (rg >= nrows) rg = nrows - 1;
            gload_lds16(gX + (size_t)rg * 256 + (off & 255), (char*)sX + base);
        }
    }
    __syncthreads();

    const int rw = ((tid >> 6) >> 1) * 32;
    const int cw = ((tid >> 6) & 1) * 64;
    const int lm = lane & 15, lq = lane >> 4;

    f32x4 acc[2][4];
#pragma unroll
    for (int tr = 0; tr < 2; tr++)
#pragma unroll
        for (int tc = 0; tc < 4; tc++) acc[tr][tc] = (f32x4){0.f, 0.f, 0.f, 0.f};

#pragma unroll
    for (int ks = 0; ks < 4; ks++) {
        int kbyte = ks * 64 + lq * 16;
        bf16x8 a[2], b[4];
#pragma unroll
        for (int tr = 0; tr < 2; tr++) {
            int r = rw + tr * 16 + lm;
            a[tr] = *(bf16x8*)((char*)sX + (r << 8) + SWZ(r, kbyte));
        }
#pragma unroll
        for (int tc = 0; tc < 4; tc++) {
            int r = cw + tc * 16 + lm;
            b[tc] = *(bf16x8*)((char*)sW + (r << 8) + SWZ(r, kbyte));
        }
#pragma unroll
        for (int tr = 0; tr < 2; tr++)
#pragma unroll
            for (int tc = 0; tc < 4; tc++)
                acc[tr][tc] = __builtin_amdgcn_mfma_f32_16x16x32_bf16(a[tr], b[tc],
                                                                      acc[tr][tc], 0, 0, 0);
    }

    const int c0 = cw + (lm << 2);
#pragma unroll
    for (int tr = 0; tr < 2; tr++) {
#pragma unroll
        for (int r = 0; r < 4; r++) {
            int row = row0 + rw + tr * 16 + lq * 4 + r;
            if (row >= nrows) continue;
            float dd = dinvp[row];
            uint q = __builtin_amdgcn_cvt_pk_fp8_f32(acc[tr][0][r] * dd,
                                                     acc[tr][1][r] * dd, 0u, false);
            q = __builtin_amdgcn_cvt_pk_fp8_f32(acc[tr][2][r] * dd,
                                                acc[tr][3][r] * dd, q, true);
            *(uint*)((unsigned char*)Y + (size_t)row * 128 + c0) = q;
        }
    }
}

// ===== FUSED layers 3+4+head: h=relu(bn3(X@Wf1)); h1=relu(h@Wf2+bf2) -> Y(f32);
//       pred=softplus(h1@Wo+bo). The 64x128 h-tile NEVER leaves LDS: after GEMM3,
//       h is written (bf16, swizzled) into the dead sX buffer, Wf2 is staged over
//       the dead sW buffer, one barrier, GEMM4. Saves one dispatch + bufC's
//       25.6MB write + 25.6MB read vs the unfused pair.
__global__ __launch_bounds__(256) void gemm34_k(const ushort* __restrict__ Xin,
                                                const ushort* __restrict__ Wt3,
                                                const ushort* __restrict__ Wt4,
                                                const float* __restrict__ sc3,
                                                const float* __restrict__ sh3,
                                                const float* __restrict__ bias4,
                                                const float* __restrict__ Wo,
                                                const float* __restrict__ bo,
                                                float* __restrict__ pred,
                                                float* __restrict__ Y, int nrows) {
    __shared__ ushort sX[64 * 128];   // X tile, then h tile (swizzled rows)
    __shared__ ushort sW[128 * 128];  // Wf1, then Wf2 (pre-swizzled layout)
    __shared__ float red[64];
    const int tid = threadIdx.x;
    const int row0 = blockIdx.x * 64;
    const int wave = tid >> 6, lane = tid & 63;
    const int rw = (wave >> 1) * 32;
    const int cw = (wave & 1) * 64;
    const int lm = lane & 15, lq = lane >> 4;
    const int c0 = cw + (lm << 2);

    // ---- stage Wf1 + X ----
    {
        const char* gW = (const char*)Wt3;
#pragma unroll
        for (int i = 0; i < 8; i++) {
            int base = (wave * 8 + i) * 1024;
            gload_lds16(gW + base + lane * 16, (char*)sW + base);
        }
        const char* gX = (const char*)Xin;
#pragma unroll
        for (int i = 0; i < 4; i++) {
            int base = (wave * 4 + i) * 1024;
            int off = base + lane * 16;
            int rg = row0 + (off >> 8);
            if (rg >= nrows) rg = nrows - 1;
            gload_lds16(gX + (size_t)rg * 256 + (off & 255), (char*)sX + base);
        }
    }
    if (tid < 64) red[tid] = 0.0f;
    // epilogue constants preloaded (latency hides under staging drain + GEMM3)
    float p3sc[4], p3sh[4], p4sh[4], woc[4];
#pragma unroll
    for (int tc = 0; tc < 4; tc++) {
        p3sc[tc] = sc3[c0 + tc];
        p3sh[tc] = sh3[c0 + tc];
        p4sh[tc] = bias4[c0 + tc];
        woc[tc] = Wo[c0 + tc];
    }
    __syncthreads();

    // ---- GEMM3 ----
    f32x4 acc[2][4];
#pragma unroll
    for (int tr = 0; tr < 2; tr++)
#pragma unroll
        for (int tc = 0; tc < 4; tc++) acc[tr][tc] = (f32x4){0.f, 0.f, 0.f, 0.f};
#pragma unroll
    for (int ks = 0; ks < 4; ks++) {
        int kbyte = ks * 64 + lq * 16;
        bf16x8 a[2], b[4];
#pragma unroll
        for (int tr = 0; tr < 2; tr++) {
            int r = rw + tr * 16 + lm;
            a[tr] = *(bf16x8*)((char*)sX + (r << 8) + SWZ(r, kbyte));
        }
#pragma unroll
        for (int tc = 0; tc < 4; tc++) {
            int r = cw + tc * 16 + lm;
            b[tc] = *(bf16x8*)((char*)sW + (r << 8) + SWZ(r, kbyte));
        }
#pragma unroll
        for (int tr = 0; tr < 2; tr++)
#pragma unroll
            for (int tc = 0; tc < 4; tc++)
                acc[tr][tc] = __builtin_amdgcn_mfma_f32_16x16x32_bf16(a[tr], b[tc],
                                                                      acc[tr][tc], 0, 0, 0);
    }
    // h = relu(acc*sc3 + sh3), packed to bf16 pairs (computed BEFORE the barrier)
    uint2 hst[2][4];
#pragma unroll
    for (int tr = 0; tr < 2; tr++)
#pragma unroll
        for (int r = 0; r < 4; r++) {
            float o0 = fmaxf(fmaf(acc[tr][0][r], p3sc[0], p3sh[0]), 0.0f);
            float o1 = fmaxf(fmaf(acc[tr][1][r], p3sc[1], p3sh[1]), 0.0f);
            float o2 = fmaxf(fmaf(acc[tr][2][r], p3sc[2], p3sh[2]), 0.0f);
            float o3 = fmaxf(fmaf(acc[tr][3][r], p3sc[3], p3sh[3]), 0.0f);
            hst[tr][r].x = (uint)f2bf(o0) | ((uint)f2bf(o1) << 16);
            hst[tr][r].y = (uint)f2bf(o2) | ((uint)f2bf(o3) << 16);
        }
    __syncthreads();  // all sX/sW reads retired -> safe to overwrite

    // write h-tile into sX (swizzled) + stage Wf2 over sW
#pragma unroll
    for (int tr = 0; tr < 2; tr++)
#pragma unroll
        for (int r = 0; r < 4; r++) {
            int lrow = rw + tr * 16 + lq * 4 + r;  // 0..63
            *(uint2*)((char*)sX + (lrow << 8) + SWZ(lrow, (uint)(c0 * 2))) = hst[tr][r];
        }
    {
        const char* gW = (const char*)Wt4;
#pragma unroll
        for (int i = 0; i < 8; i++) {
            int base = (wave * 8 + i) * 1024;
            gload_lds16(gW + base + lane * 16, (char*)sW + base);
        }
    }
    __syncthreads();  // h + Wf2 ready

    // ---- GEMM4 ----
#pragma unroll
    for (int tr = 0; tr < 2; tr++)
#pragma unroll
        for (int tc = 0; tc < 4; tc++) acc[tr][tc] = (f32x4){0.f, 0.f, 0.f, 0.f};
#pragma unroll
    for (int ks = 0; ks < 4; ks++) {
        int kbyte = ks * 64 + lq * 16;
        bf16x8 a[2], b[4];
#pragma unroll
        for (int tr = 0; tr < 2; tr++) {
            int r = rw + tr * 16 + lm;
            a[tr] = *(bf16x8*)((char*)sX + (r << 8) + SWZ(r, kbyte));
        }
#pragma unroll
        for (int tc = 0; tc < 4; tc++) {
            int r = cw + tc * 16 + lm;
            b[tc] = *(bf16x8*)((char*)sW + (r << 8) + SWZ(r, kbyte));
        }
#pragma unroll
        for (int tr = 0; tr < 2; tr++)
#pragma unroll
            for (int tc = 0; tc < 4; tc++)
                acc[tr][tc] = __builtin_amdgcn_mfma_f32_16x16x32_bf16(a[tr], b[tc],
                                                                      acc[tr][tc], 0, 0, 0);
    }
    // epilogue 4: h1 = relu(acc + bf2) -> f32 out; head partials
    float part[8];
#pragma unroll
    for (int i = 0; i < 8; i++) part[i] = 0.0f;
#pragma unroll
    for (int tr = 0; tr < 2; tr++) {
#pragma unroll
        for (int r = 0; r < 4; r++) {
            int lrow = rw + tr * 16 + lq * 4 + r;
            int row = row0 + lrow;
            if (row >= nrows) continue;
            float o0 = fmaxf(acc[tr][0][r] + p4sh[0], 0.0f);
            float o1 = fmaxf(acc[tr][1][r] + p4sh[1], 0.0f);
            float o2 = fmaxf(acc[tr][2][r] + p4sh[2], 0.0f);
            float o3 = fmaxf(acc[tr][3][r] + p4sh[3], 0.0f);
            f32x4 st = {o0, o1, o2, o3};
            __builtin_nontemporal_store(st, (f32x4*)(Y + (size_t)row * 128 + c0));
            part[tr * 4 + r] = fmaf(o0, woc[0],
                               fmaf(o1, woc[1],
                               fmaf(o2, woc[2],
                               fmaf(o3, woc[3], part[tr * 4 + r]))));
        }
    }
#pragma unroll
    for (int tr = 0; tr < 2; tr++)
#pragma unroll
        for (int r = 0; r < 4; r++)
            atomicAdd(&red[rw + tr * 16 + lq * 4 + r], part[tr * 4 + r]);
    __syncthreads();
    if (tid < 64) {
        int row = row0 + tid;
        if (row < nrows) {
            float xv = red[tid] + bo[0];
            pred[row] = fmaxf(xv, 0.0f) + log1pf(expf(-fabsf(xv)));  // softplus
        }
    }
}

extern "C" void kernel_launch(void* const* d_in, const int* in_sizes, int n_in,
                              void* d_out, int out_size, void* d_ws, size_t ws_size,
                              hipStream_t stream) {
    const float* x = (const float*)d_in[0];
    const int* ei = (const int*)d_in[1];
    const int N = in_sizes[0] / 128;
    const int E = in_sizes[1] / 2;
    const int* srcv = ei;
    const int* dstv = ei + E;
    const float* W1 = (const float*)d_in[2];  const float* b1 = (const float*)d_in[3];
    const float* W2 = (const float*)d_in[4];  const float* b2 = (const float*)d_in[5];
    const float* Wf1 = (const float*)d_in[6]; const float* bf1 = (const float*)d_in[7];
    const float* Wf2 = (const float*)d_in[8]; const float* bf2 = (const float*)d_in[9];
    const float* Wo = (const float*)d_in[10]; const float* bo = (const float*)d_in[11];
    const float* g1 = (const float*)d_in[12], *be1 = (const float*)d_in[13],
               *m1 = (const float*)d_in[14], *v1 = (const float*)d_in[15];
    const float* g2 = (const float*)d_in[16], *be2 = (const float*)d_in[17],
               *m2 = (const float*)d_in[18], *v2 = (const float*)d_in[19];
    const float* g3 = (const float*)d_in[20], *be3 = (const float*)d_in[21],
               *m3 = (const float*)d_in[22], *v3 = (const float*)d_in[23];

    // ---- workspace carve-up ----
    char* ws = (char*)d_ws;
    size_t off = 0;
    auto carve = [&](size_t bytes) {
        char* p = ws + off;
        off = (off + bytes + 255) & ~(size_t)255;
        return p;
    };
    const int NB = (N + 255) >> 8;
    const int STRIDE = ((E / NB + 511) + 255) & ~255;  // mean + ~8 sigma slack
    int* bcur = (int*)carve((size_t)MAXNB * 4);
    int2* rowptr = (int2*)carve((size_t)N * 8);
    int* col = (int*)carve((size_t)NB * STRIDE * 4);
    int* coarse = (int*)carve((size_t)NB * STRIDE * 4);
    float* dinv = (float*)carve((size_t)N * 4);
    unsigned char* bufA8 = (unsigned char*)carve((size_t)N * 128 + 16384);  // fp8 hs
    ushort* bufB = (ushort*)carve((size_t)N * 128 * 2 + 16384);             // bf16 swz
    ushort* Wt1 = (ushort*)carve(128 * 128 * 2);
    ushort* Wt2 = (ushort*)carve(128 * 128 * 2);
    ushort* Wtf1 = (ushort*)carve(128 * 128 * 2);
    ushort* Wtf2 = (ushort*)carve(128 * 128 * 2);
    float* bnc = (float*)carve(768 * 4);  // sc1|sh1|sc2|sh2|sc3|sh3

    float* out_pred = (float*)d_out;
    float* out_h1 = out_pred + N;

    const int gblocks = (N + 63) / 64;
    const int tblocks = (E + 4095) / 4096;
    const int wblocks = (N + 3) / 4;

    // ---- prep (weights + bcur + BN consts) ----
    prep_k<<<257, 256, 0, stream>>>(W1, W2, Wf1, Wf2, Wt1, Wt2, Wtf1, Wtf2, bcur, NB,
                                    STRIDE, b1, g1, be1, m1, v1, b2, g2, be2, m2, v2,
                                    bf1, g3, be3, m3, v3, bnc);
    // ---- CSR build ----
    bucketA_k<<<tblocks, 256, 0, stream>>>(srcv, dstv, bcur, coarse, E, NB);
    bucketB_k<<<NB, 256, 0, stream>>>(coarse, bcur, rowptr, col, dinv, N, STRIDE);

    // layer 1: hs1 = dinv*(x@W1) (fp8)
    mfma_gemm_k<0, 1><<<gblocks, 256, 0, stream>>>(x, Wt1, dinv, bufA8, N);
    // conv1 + bn1 + relu -> bf16 (swizzled rows)
    gather_k<<<wblocks, 256, 0, stream>>>(bufA8, rowptr, col, dinv,
                                          bnc, bnc + 128, bufB, N);
    // layer 2 GEMM: hs2 = dinv*(h@W2) (fp8)
    mfma_gemm_k<0, 0><<<gblocks, 256, 0, stream>>>(bufB, Wt2, dinv, bufA8, N);
    // conv2 + bn2 + relu -> bf16 (swizzled rows)
    gather_k<<<wblocks, 256, 0, stream>>>(bufA8, rowptr, col, dinv,
                                          bnc + 256, bnc + 384, bufB, N);
    // FUSED layers 3+4+head: h-tile stays in LDS; writes out_h1 + pred only
    gemm34_k<<<gblocks, 256, 0, stream>>>(bufB, Wtf1, Wtf2, bnc + 512, bnc + 640,
                                          bf2, Wo, bo, out_pred, out_h1, N);
}